// Round 8
// baseline (487.406 us; speedup 1.0000x reference)
//
#include <hip/hip_runtime.h>
#include <hip/hip_bf16.h>

using bf16 = __hip_bfloat16;
typedef short s16x8 __attribute__((ext_vector_type(8)));
typedef short s16x4 __attribute__((ext_vector_type(4)));
typedef float f32x4 __attribute__((ext_vector_type(4)));
typedef float f32x2 __attribute__((ext_vector_type(2)));

#define BSZ   8
#define NN    15135
#define FF    64
#define GG    73
#define HH    256
#define EE    242160
#define K1P   160                 // 137 padded to mult of 32
#define MREAL (BSZ * NN)          // 121080
#define MPAD  (946 * 128)         // 121088
#define HFC   512
#define NCHUNK 64
#define NCHUNKS ((NN + NCHUNK - 1) / NCHUNK)   // 237
#define SCANB  ((NN + 255) / 256)              // 60
// fp8 pre-scale: hw stored as e4m3(64*v); x64 folded into WT, 1/64 into csr_norm & dinv
#define FP8_INV_SCALE 0.015625f

#define GLOAD_LDS16(gp, lp)                                                     \
    __builtin_amdgcn_global_load_lds(                                           \
        (const __attribute__((address_space(1))) void*)(gp),                    \
        (__attribute__((address_space(3))) void*)(lp), 16, 0, 0)

// Column permutation applied to the 256-wide GEMM output space.
// Epilogue stores col c at byte position sigma(c) = (c&192) + 4*(c&15) + ((c>>4)&3);
// colmap(p) = sigma^-1(p). Aggregation is element-wise over rows, so a uniform
// column permutation commutes with it; consumers compensate via colmap.
__device__ __forceinline__ int colmap(int p) {
    return (p & 192) | ((p & 3) << 4) | ((p >> 2) & 15);
}

// ------------------------------------------------- fused prep: h0 | WT | zeros
// Also zeroes deg counters, g accumulator and the k_setup sync counter
// (runs strictly before k_setup in stream order).
#define PREP_H0_CNT (MREAL * (K1P / 8))
#define PREP_W1_CNT (256 * K1P)
#define PREP_W23_CNT 65536
#define PREP_TOT (PREP_H0_CNT + PREP_W1_CNT + 2 * PREP_W23_CNT + NN + MREAL + 64)
__global__ void k_prep(const float* __restrict__ x, const float* __restrict__ gl,
                       bf16* __restrict__ h0,
                       const float* __restrict__ W1, const float* __restrict__ W2,
                       const float* __restrict__ W3, bf16* __restrict__ W1T,
                       bf16* __restrict__ W2T, bf16* __restrict__ W3T,
                       int* __restrict__ cnt, float* __restrict__ g,
                       int* __restrict__ sync) {
    int idx = blockIdx.x * blockDim.x + threadIdx.x;
    if (idx < PREP_H0_CNT) {
        int m = idx / (K1P / 8);
        int q = idx - m * (K1P / 8);
        int j0 = q * 8;
        int n = m % NN;
        s16x8 o;
        #pragma unroll
        for (int k = 0; k < 8; ++k) {
            int j = j0 + k;
            float val;
            if (j < FF) val = x[(size_t)m * FF + j];
            else if (j < FF + GG) val = gl[(size_t)n * GG + (j - FF)];
            else val = 0.f;
            o[k] = (short)__bfloat16_as_ushort(__float2bfloat16(val));
        }
        *(s16x8*)&h0[(size_t)m * K1P + j0] = o;
        return;
    }
    idx -= PREP_H0_CNT;
    if (idx < PREP_W1_CNT) {
        int nn = idx / K1P, kk = idx - nn * K1P;
        W1T[idx] = __float2bfloat16(
            kk < FF + GG ? 64.f * W1[(size_t)kk * 256 + nn] : 0.f);
        return;
    }
    idx -= PREP_W1_CNT;
    if (idx < PREP_W23_CNT) {
        int nn = idx >> 8, kk = idx & 255;
        W2T[idx] = __float2bfloat16(64.f * W2[(size_t)colmap(kk) * 256 + nn]);
        return;
    }
    idx -= PREP_W23_CNT;
    if (idx < PREP_W23_CNT) {
        int nn = idx >> 8, kk = idx & 255;
        W3T[idx] = __float2bfloat16(64.f * W3[(size_t)colmap(kk) * 256 + nn]);
        return;
    }
    idx -= PREP_W23_CNT;
    if (idx < NN) { cnt[idx] = 0; return; }
    idx -= NN;
    if (idx < MREAL) { g[idx] = 0.f; return; }
    idx -= MREAL;
    if (idx < 64) sync[idx] = 0;
}

// ------------------------------------------- fused setup: deg+scan+dis+csr
// One kernel replaces k_deg/k_scanA/k_scanB/k_scanC/k_csr via device-scope
// grid barriers. NB_SETUP=240 blocks x 256 thr: co-resident (<=1 block/CU).
// Barrier: atomic arrive + atomic spin-read (device-coherent across XCDs),
// __threadfence release/acquire. Counter monotone; zeroed by k_prep.
#define NB_SETUP 240
__device__ __forceinline__ void gbar(int* sync, int target) {
    __syncthreads();
    if (threadIdx.x == 0) {
        __threadfence();
        atomicAdd(sync, 1);
        while (atomicAdd(sync, 0) < target) __builtin_amdgcn_s_sleep(8);
        __threadfence();
    }
    __syncthreads();
}

__global__ __launch_bounds__(256)
void k_setup(const int* __restrict__ erow, const int* __restrict__ ecol,
             int* __restrict__ cnt, int* __restrict__ offs,
             int* __restrict__ cursor, int* __restrict__ bsum,
             float* __restrict__ dis, float* __restrict__ dinv,
             int2* __restrict__ cpack, int* __restrict__ sync) {
    __shared__ int ws[4];
    const int tid = threadIdx.x, bid = blockIdx.x;
    const int gsz = NB_SETUP * 256;
    const int gid = bid * 256 + tid;

    // phase 1: degree histogram
    for (int i = gid; i < EE; i += gsz) atomicAdd(&cnt[ecol[i]], 1);
    gbar(sync, NB_SETUP);

    // phase 2: per-chunk (256-wide) inclusive scan; 60 chunks on blocks 0..59
    if (bid < SCANB) {
        int i = bid * 256 + tid;
        int lane = tid & 63, wid = tid >> 6;
        int v = (i < NN) ? cnt[i] : 0;
        int s = v;
        #pragma unroll
        for (int off = 1; off < 64; off <<= 1) {
            int t = __shfl_up(s, off);
            if (lane >= off) s += t;
        }
        if (lane == 63) ws[wid] = s;
        __syncthreads();
        int pre = 0;
        #pragma unroll
        for (int w = 0; w < 4; ++w) pre += (w < wid) ? ws[w] : 0;
        int incl = pre + s;
        if (i < NN) cursor[i] = incl;
        if (tid == 255) bsum[bid] = incl;
    }
    gbar(sync, 2 * NB_SETUP);

    // phase 3: block 0 scans the 60 block sums (exclusive)
    if (bid == 0 && tid < 64) {
        int v = (tid < SCANB) ? bsum[tid] : 0;
        int s = v;
        #pragma unroll
        for (int off = 1; off < 64; off <<= 1) {
            int xx = __shfl_up(s, off);
            if (tid >= off) s += xx;
        }
        if (tid < SCANB) bsum[tid] = s - v;
        if (tid == 63) offs[NN] = s;
    }
    gbar(sync, 3 * NB_SETUP);

    // phase 4: exclusive offsets + dis/dinv
    if (bid < SCANB) {
        int i = bid * 256 + tid;
        if (i < NN) {
            int v = cnt[i];
            int excl = cursor[i] - v + bsum[bid];
            offs[i] = excl;
            cursor[i] = excl;
            float d = (float)(v + 1);
            dis[i]  = rsqrtf(d);
            dinv[i] = (1.0f / d) * FP8_INV_SCALE;
        }
    }
    gbar(sync, 4 * NB_SETUP);

    // phase 5: CSR fill (packed row+norm)
    for (int i = gid; i < EE; i += gsz) {
        int r = erow[i], c = ecol[i];
        int p = atomicAdd(&cursor[c], 1);
        cpack[p] = make_int2(r, __float_as_int(dis[r] * dis[c] * FP8_INV_SCALE));
    }
}

// ---------------------------------------------------------------- MFMA GEMM
// BM=64 x BN=256: A read exactly once; B (128KB) L2-resident per XCD.
// C (fp8, x64 via pre-scaled WT): [row][256] sigma-layout, packed dword stores.
#define BK 32
template <int K>
__global__ __launch_bounds__(256)
void k_gemm(const bf16* __restrict__ A, const bf16* __restrict__ BT,
            unsigned char* __restrict__ C) {
    __shared__ __align__(16) short As[64 * BK];      // 4 KB
    __shared__ __align__(16) short Bs[256 * BK];     // 16 KB
    const int tid  = threadIdx.x;
    const int bm   = blockIdx.x * 64;
    const int lane = tid & 63, wave = tid >> 6;
    const int wn   = wave * 64;
    const int fr   = lane & 15, quad = lane >> 4;
    const int r    = tid >> 2;           // 0..63
    const int c    = (tid & 3) * 8;      // shorts: 0,8,16,24

    const bf16* Ap = A  + (size_t)(bm + r) * K + c;
    const bf16* Bp = BT + (size_t)r * K + c;        // rows 0..63 (quarter 0)
    short* AsT = As + tid * 8;                      // byte offset tid*16
    short* BsT = Bs + tid * 8;

    f32x4 acc[4][4] = {};

    for (int k0 = 0; k0 < K; k0 += BK) {
        GLOAD_LDS16(Ap + k0, AsT);
        #pragma unroll
        for (int q = 0; q < 4; ++q)
            GLOAD_LDS16(Bp + (size_t)(q * 64) * K + k0, BsT + q * 64 * BK);
        __syncthreads();
        s16x8 af[4], bfv[4];
        #pragma unroll
        for (int i = 0; i < 4; ++i)
            af[i] = *(const s16x8*)&As[(i * 16 + fr) * BK + quad * 8];
        #pragma unroll
        for (int j = 0; j < 4; ++j)
            bfv[j] = *(const s16x8*)&Bs[(wn + j * 16 + fr) * BK + quad * 8];
        #pragma unroll
        for (int i = 0; i < 4; ++i)
            #pragma unroll
            for (int j = 0; j < 4; ++j)
                acc[i][j] = __builtin_amdgcn_mfma_f32_16x16x32_bf16(
                    af[i], bfv[j], acc[i][j], 0, 0, 0);
        __syncthreads();
    }

    // epilogue: packed dword store per row (sigma-layout); x64 already in WT
    #pragma unroll
    for (int i = 0; i < 4; ++i) {
        int rbase = bm + i * 16 + quad * 4;
        #pragma unroll
        for (int rr = 0; rr < 4; ++rr) {
            int row = rbase + rr;
            if (row >= MREAL) continue;
            unsigned wpack = (unsigned)__builtin_amdgcn_cvt_pk_fp8_f32(
                acc[i][0][rr], acc[i][1][rr], 0, false);
            wpack = (unsigned)__builtin_amdgcn_cvt_pk_fp8_f32(
                acc[i][2][rr], acc[i][3][rr], (int)wpack, true);
            *(unsigned*)&C[(size_t)row * 256 + wn + fr * 4] = wpack;
        }
    }
}

// ------------------------------------------------------- aggregate + elu + fc
// hw fp8 [b*NN+n][256] (x64, sigma-layout); hout bf16 [b*NN+n][256] (sigma).
// Batch-partitioned for XCD L2 residency (blockIdx%8 -> XCD, plane 3.87MB<4MB).
// One node per wave; per-edge metadata wave-uniform -> scalar pipe.
// 16-deep gather unroll: latency-bound (all pipes <50%), double in-flight loads.
#define AGG_GRP 512                       // node groups per batch
#define AGG_STRIDE (AGG_GRP * 4)          // 2048 waves per batch
__global__ __launch_bounds__(256)
void k_agg(const unsigned char* __restrict__ hw, bf16* __restrict__ hout,
           const int* __restrict__ offs, const int2* __restrict__ cpack,
           const float* __restrict__ dinv,
           const float* __restrict__ bias, const float* __restrict__ fcW,
           float* __restrict__ g, int writeH) {
    const int b    = blockIdx.x & 7;
    const int grp  = blockIdx.x >> 3;          // 0..AGG_GRP-1
    const int wid  = threadIdx.x >> 6;         // 0..3
    const int lane = threadIdx.x & 63;
    const int wv   = grp * 4 + wid;            // 0..AGG_STRIDE-1
    const unsigned c4 = lane * 4;

    const unsigned char* hwb = hw + (size_t)b * NN * 256;

    float bias4[4], fw4[4];
    #pragma unroll
    for (int k = 0; k < 4; ++k) {
        int cl = colmap((int)c4 + k);
        bias4[k] = bias[cl];
        fw4[k]   = fcW[3 * cl];
    }

    for (int v0 = wv; v0 < NN; v0 += AGG_STRIDE) {
        const int v   = __builtin_amdgcn_readfirstlane(v0);
        const int beg = __builtin_amdgcn_readfirstlane(offs[v]);
        const int end = __builtin_amdgcn_readfirstlane(offs[v + 1]);
        const float di = dinv[v];
        f32x2 a01, a23;
        {
            unsigned q = *(const unsigned*)(hwb + (((unsigned)v) << 8) + c4);
            f32x2 t0 = __builtin_amdgcn_cvt_pk_f32_fp8(q, false);
            f32x2 t1 = __builtin_amdgcn_cvt_pk_f32_fp8(q, true);
            f32x2 dd = {di, di};
            a01 = dd * t0;
            a23 = dd * t1;
        }

        #define EDGE1(qv, mv) {                                            \
            f32x2 t0 = __builtin_amdgcn_cvt_pk_f32_fp8((qv), false);       \
            f32x2 t1 = __builtin_amdgcn_cvt_pk_f32_fp8((qv), true);        \
            f32x2 mm = {(mv), (mv)};                                       \
            a01 += mm * t0;                                                \
            a23 += mm * t1; }

        int e = beg;
        while (e + 16 <= end) {
            int2 ep[16];
            #pragma unroll
            for (int u = 0; u < 16; ++u) ep[u] = cpack[e + u];
            unsigned q[16];
            #pragma unroll
            for (int u = 0; u < 16; ++u)
                q[u] = *(const unsigned*)(hwb + (((unsigned)ep[u].x) << 8) + c4);
            #pragma unroll
            for (int u = 0; u < 16; ++u) EDGE1(q[u], __int_as_float(ep[u].y));
            e += 16;
        }
        if (e + 8 <= end) {
            int2 ep[8];
            #pragma unroll
            for (int u = 0; u < 8; ++u) ep[u] = cpack[e + u];
            unsigned q[8];
            #pragma unroll
            for (int u = 0; u < 8; ++u)
                q[u] = *(const unsigned*)(hwb + (((unsigned)ep[u].x) << 8) + c4);
            #pragma unroll
            for (int u = 0; u < 8; ++u) EDGE1(q[u], __int_as_float(ep[u].y));
            e += 8;
        }
        if (e + 4 <= end) {
            int2 ep[4];
            #pragma unroll
            for (int u = 0; u < 4; ++u) ep[u] = cpack[e + u];
            unsigned q[4];
            #pragma unroll
            for (int u = 0; u < 4; ++u)
                q[u] = *(const unsigned*)(hwb + (((unsigned)ep[u].x) << 8) + c4);
            #pragma unroll
            for (int u = 0; u < 4; ++u) EDGE1(q[u], __int_as_float(ep[u].y));
            e += 4;
        }
        if (e + 2 <= end) {
            int2 ep0 = cpack[e], ep1 = cpack[e + 1];
            unsigned q0 = *(const unsigned*)(hwb + (((unsigned)ep0.x) << 8) + c4);
            unsigned q1 = *(const unsigned*)(hwb + (((unsigned)ep1.x) << 8) + c4);
            EDGE1(q0, __int_as_float(ep0.y));
            EDGE1(q1, __int_as_float(ep1.y));
            e += 2;
        }
        if (e < end) {
            int2 ep0 = cpack[e];
            unsigned q0 = *(const unsigned*)(hwb + (((unsigned)ep0.x) << 8) + c4);
            EDGE1(q0, __int_as_float(ep0.y));
        }
        #undef EDGE1

        float acc4[4] = {a01[0], a01[1], a23[0], a23[1]};
        float p = 0.f;
        s16x4 o4;
        #pragma unroll
        for (int k = 0; k < 4; ++k) {
            float hv = acc4[k] + bias4[k];
            hv = hv > 0.f ? hv : (__expf(hv) - 1.0f);
            o4[k] = (short)__bfloat16_as_ushort(__float2bfloat16(hv));
            p += hv * fw4[k];
        }
        if (writeH)
            *(s16x4*)&hout[((size_t)b * NN + v) * 256 + c4] = o4;

        #pragma unroll
        for (int off = 32; off; off >>= 1) p += __shfl_xor(p, off);
        if (lane == 0) g[(size_t)b * NN + v] += p;
    }
}

// ------------------------------------------------------------ lin1 partials
__global__ __launch_bounds__(256)
void k_lin1(const float* __restrict__ g, const float* __restrict__ fcb,
            const float* __restrict__ W, float* __restrict__ zpart) {
    const int ny = blockIdx.x;
    const int n0 = ny * NCHUNK;
    const int cnt = min(NCHUNK, NN - n0);
    const int tid = threadIdx.x;
    __shared__ float sg[8][NCHUNK];
    float fb = fcb[0];
    for (int idx = tid; idx < 8 * NCHUNK; idx += 256) {
        int b = idx / NCHUNK, nn = idx - b * NCHUNK;
        sg[b][nn] = (nn < cnt) ? (g[(size_t)b * NN + n0 + nn] + fb) : 0.f;
    }
    __syncthreads();
    float2 acc[8] = {};
    for (int nn = 0; nn < cnt; ++nn) {
        float2 w = *(const float2*)&W[(size_t)(n0 + nn) * HFC + tid * 2];
        #pragma unroll
        for (int b = 0; b < 8; ++b) {
            float gv = sg[b][nn];
            acc[b].x += gv * w.x;
            acc[b].y += gv * w.y;
        }
    }
    #pragma unroll
    for (int b = 0; b < 8; ++b)
        *(float2*)&zpart[(size_t)ny * 4096 + b * 512 + tid * 2] = acc[b];
}

// ----------------------------- lin1 reduce + lin2 + log_softmax (one launch)
// 8 blocks (one per batch) x 512 threads.
__global__ __launch_bounds__(512)
void k_lin2(const float* __restrict__ zpart, const float* __restrict__ l1b,
            const float* __restrict__ W2, const float* __restrict__ l2b,
            float* __restrict__ out) {
    __shared__ float r0[512], r1[512];
    const int b = blockIdx.x, t = threadIdx.x;
    float s = 0.f;
    for (int c = 0; c < NCHUNKS; ++c) s += zpart[(size_t)c * 4096 + b * 512 + t];
    float zv = s + l1b[t];
    zv = zv > 0.f ? zv : (__expf(zv) - 1.0f);
    r0[t] = zv * W2[t * 2 + 0];
    r1[t] = zv * W2[t * 2 + 1];
    __syncthreads();
    for (int st = 256; st; st >>= 1) {
        if (t < st) { r0[t] += r0[t + st]; r1[t] += r1[t + st]; }
        __syncthreads();
    }
    if (t == 0) {
        float o0 = r0[0] + l2b[0], o1 = r1[0] + l2b[1];
        float m = fmaxf(o0, o1);
        float lse = m + logf(expf(o0 - m) + expf(o1 - m));
        out[b * 2 + 0] = o0 - lse;
        out[b * 2 + 1] = o1 - lse;
    }
}

// ---------------------------------------------------------------- launcher
extern "C" void kernel_launch(void* const* d_in, const int* in_sizes, int n_in,
                              void* d_out, int out_size, void* d_ws, size_t ws_size,
                              hipStream_t stream) {
    const float* x    = (const float*)d_in[0];
    const int*   eidx = (const int*)d_in[2];      // [0..E) = row, [E..2E) = col
    const float* gl   = (const float*)d_in[3];
    const float* W1   = (const float*)d_in[4];
    const float* b1   = (const float*)d_in[5];
    const float* W2   = (const float*)d_in[6];
    const float* b2   = (const float*)d_in[7];
    const float* W3   = (const float*)d_in[8];
    const float* b3   = (const float*)d_in[9];
    const float* fcW  = (const float*)d_in[10];
    const float* fcb  = (const float*)d_in[11];
    const float* l1W  = (const float*)d_in[12];
    const float* l1b  = (const float*)d_in[13];
    const float* l2W  = (const float*)d_in[14];
    const float* l2b  = (const float*)d_in[15];
    float* out = (float*)d_out;

    size_t off = 0;
    auto alloc = [&](size_t bytes) {
        void* p = (char*)d_ws + off;
        off += (bytes + 255) & ~(size_t)255;
        return p;
    };
    bf16* bufA          = (bf16*)alloc((size_t)MPAD * 256 * 2);          // 62 MB
    unsigned char* bufC = (unsigned char*)alloc((size_t)MPAD * 256);     // 31 MB
    bf16* W1T      = (bf16*)alloc(256 * K1P * 2);
    bf16* W2T      = (bf16*)alloc(256 * 256 * 2);
    bf16* W3T      = (bf16*)alloc(256 * 256 * 2);
    int*  deg_cnt  = (int*)alloc(NN * 4);
    int*  offs     = (int*)alloc((NN + 1) * 4);
    int*  cursor   = (int*)alloc(NN * 4);
    int*  bsum     = (int*)alloc(SCANB * 4);
    float* dis     = (float*)alloc(NN * 4);
    float* dinv    = (float*)alloc(NN * 4);
    int2* cpack    = (int2*)alloc((size_t)EE * 8);
    float* g       = (float*)alloc((size_t)BSZ * NN * 4);
    int*  sync     = (int*)alloc(64 * 4);

    // zpart aliases bufC: dead after the last k_agg
    float* zpart = (float*)bufC;                              // 3.9 MB

    const int* erow = eidx;
    const int* ecol = eidx + EE;

    // 1. fused prep (h0, WT x3, zero cnt/g/sync)
    k_prep<<<(PREP_TOT + 255) / 256, 256, 0, stream>>>(
        x, gl, bufA, W1, W2, W3, W1T, W2T, W3T, deg_cnt, g, sync);

    // 2. fused setup (deg + scan + dis/dinv + csr), grid-barrier internal
    k_setup<<<NB_SETUP, 256, 0, stream>>>(erow, ecol, deg_cnt, offs, cursor,
                                          bsum, dis, dinv, cpack, sync);

    dim3 ggrid(MPAD / 64);
    dim3 agrid(8 * AGG_GRP);

    // layer 1
    k_gemm<K1P><<<ggrid, 256, 0, stream>>>(bufA, W1T, bufC);
    k_agg<<<agrid, 256, 0, stream>>>(bufC, bufA, offs, cpack, dinv,
                                     b1, fcW + 0, g, 1);
    // layer 2
    k_gemm<256><<<ggrid, 256, 0, stream>>>(bufA, W2T, bufC);
    k_agg<<<agrid, 256, 0, stream>>>(bufC, bufA, offs, cpack, dinv,
                                     b2, fcW + 1, g, 1);
    // layer 3 (h3 not materialized; only fc contribution)
    k_gemm<256><<<ggrid, 256, 0, stream>>>(bufA, W3T, bufC);
    k_agg<<<agrid, 256, 0, stream>>>(bufC, bufA, offs, cpack, dinv,
                                     b3, fcW + 2, g, 0);

    k_lin1<<<NCHUNKS, 256, 0, stream>>>(g, fcb, l1W, zpart);
    k_lin2<<<8, 512, 0, stream>>>(zpart, l1b, l2W, l2b, out);
}

// Round 9
// 457.680 us; speedup vs baseline: 1.0649x; 1.0649x over previous
//
#include <hip/hip_runtime.h>
#include <hip/hip_bf16.h>

using bf16 = __hip_bfloat16;
typedef short s16x8 __attribute__((ext_vector_type(8)));
typedef short s16x4 __attribute__((ext_vector_type(4)));
typedef float f32x4 __attribute__((ext_vector_type(4)));
typedef float f32x2 __attribute__((ext_vector_type(2)));

#define BSZ   8
#define NN    15135
#define FF    64
#define GG    73
#define HH    256
#define EE    242160
#define K1P   160                 // 137 padded to mult of 32
#define MREAL (BSZ * NN)          // 121080
#define MPAD  (946 * 128)         // 121088
#define HFC   512
#define NCHUNK 64
#define NCHUNKS ((NN + NCHUNK - 1) / NCHUNK)   // 237
#define SCANB  ((NN + 255) / 256)              // 60
// fp8 pre-scale: hw stored as e4m3(64*v); x64 folded into WT, 1/64 into csr_norm & dinv
#define FP8_INV_SCALE 0.015625f

#define GLOAD_LDS16(gp, lp)                                                     \
    __builtin_amdgcn_global_load_lds(                                           \
        (const __attribute__((address_space(1))) void*)(gp),                    \
        (__attribute__((address_space(3))) void*)(lp), 16, 0, 0)

// Column permutation applied to the 256-wide GEMM output space.
// Epilogue stores col c at byte position sigma(c) = (c&192) + 4*(c&15) + ((c>>4)&3);
// colmap(p) = sigma^-1(p). Aggregation is element-wise over rows, so a uniform
// column permutation commutes with it; consumers compensate via colmap.
__device__ __forceinline__ int colmap(int p) {
    return (p & 192) | ((p & 3) << 4) | ((p >> 2) & 15);
}

// ------------------------------------------------- fused prep: h0 | WT | zeros
// Also zeroes deg counters, g accumulator and the k_setup sync counter
// (runs strictly before k_setup in stream order).
#define PREP_H0_CNT (MREAL * (K1P / 8))
#define PREP_W1_CNT (256 * K1P)
#define PREP_W23_CNT 65536
#define PREP_TOT (PREP_H0_CNT + PREP_W1_CNT + 2 * PREP_W23_CNT + NN + MREAL + 64)
__global__ void k_prep(const float* __restrict__ x, const float* __restrict__ gl,
                       bf16* __restrict__ h0,
                       const float* __restrict__ W1, const float* __restrict__ W2,
                       const float* __restrict__ W3, bf16* __restrict__ W1T,
                       bf16* __restrict__ W2T, bf16* __restrict__ W3T,
                       int* __restrict__ cnt, float* __restrict__ g,
                       int* __restrict__ sync) {
    int idx = blockIdx.x * blockDim.x + threadIdx.x;
    if (idx < PREP_H0_CNT) {
        int m = idx / (K1P / 8);
        int q = idx - m * (K1P / 8);
        int j0 = q * 8;
        int n = m % NN;
        s16x8 o;
        #pragma unroll
        for (int k = 0; k < 8; ++k) {
            int j = j0 + k;
            float val;
            if (j < FF) val = x[(size_t)m * FF + j];
            else if (j < FF + GG) val = gl[(size_t)n * GG + (j - FF)];
            else val = 0.f;
            o[k] = (short)__bfloat16_as_ushort(__float2bfloat16(val));
        }
        *(s16x8*)&h0[(size_t)m * K1P + j0] = o;
        return;
    }
    idx -= PREP_H0_CNT;
    if (idx < PREP_W1_CNT) {
        int nn = idx / K1P, kk = idx - nn * K1P;
        W1T[idx] = __float2bfloat16(
            kk < FF + GG ? 64.f * W1[(size_t)kk * 256 + nn] : 0.f);
        return;
    }
    idx -= PREP_W1_CNT;
    if (idx < PREP_W23_CNT) {
        int nn = idx >> 8, kk = idx & 255;
        W2T[idx] = __float2bfloat16(64.f * W2[(size_t)colmap(kk) * 256 + nn]);
        return;
    }
    idx -= PREP_W23_CNT;
    if (idx < PREP_W23_CNT) {
        int nn = idx >> 8, kk = idx & 255;
        W3T[idx] = __float2bfloat16(64.f * W3[(size_t)colmap(kk) * 256 + nn]);
        return;
    }
    idx -= PREP_W23_CNT;
    if (idx < NN) { cnt[idx] = 0; return; }
    idx -= NN;
    if (idx < MREAL) { g[idx] = 0.f; return; }
    idx -= MREAL;
    if (idx < 64) sync[idx] = 0;
}

// ------------------------------------------- fused setup: deg+scan+dis+csr
// 240 blocks x 1024 threads (1 block/CU, co-resident; 245760 threads >= EE so
// the two atomic phases are ONE atomic per thread). 2 grid barriers only:
//   phase 1 (all): degree histogram          -> gbar
//   phase 2 (block 0): full scan + offs + dis/dinv (15 x 1024-wide chunks)
//                                            -> gbar
//   phase 3 (all): CSR fill
// Spin uses a relaxed AGENT-scope atomic LOAD (not RMW) so 239 spinners don't
// serialize the sync cacheline against arrivers.
#define NB_SETUP 240
#define TS 1024
__device__ __forceinline__ void gbar(int* sync, int target) {
    __syncthreads();
    if (threadIdx.x == 0) {
        __threadfence();
        atomicAdd(sync, 1);
        while (__hip_atomic_load(sync, __ATOMIC_RELAXED,
                                 __HIP_MEMORY_SCOPE_AGENT) < target)
            __builtin_amdgcn_s_sleep(2);
        __threadfence();
    }
    __syncthreads();
}

__global__ __launch_bounds__(1024)
void k_setup(const int* __restrict__ erow, const int* __restrict__ ecol,
             int* __restrict__ cnt, int* __restrict__ offs,
             int* __restrict__ cursor, int* __restrict__ bsum,
             float* __restrict__ dis, float* __restrict__ dinv,
             int2* __restrict__ cpack, int* __restrict__ sync) {
    __shared__ int ws2[16];
    __shared__ int carry;
    const int tid = threadIdx.x, bid = blockIdx.x;
    const int gid = bid * TS + tid;

    // phase 1: degree histogram, one edge per thread (fire-and-forget atomic)
    if (gid < EE) atomicAdd(&cnt[ecol[gid]], 1);
    gbar(sync, NB_SETUP);

    // phase 2: block 0 scans all NN degrees, writes offs/cursor/dis/dinv
    if (bid == 0) {
        if (tid == 0) carry = 0;
        __syncthreads();
        for (int base = 0; base < NN; base += TS) {
            int i = base + tid;
            int v = (i < NN) ? cnt[i] : 0;
            int lane = tid & 63, w = tid >> 6;
            int s = v;
            #pragma unroll
            for (int off = 1; off < 64; off <<= 1) {
                int t = __shfl_up(s, off);
                if (lane >= off) s += t;
            }
            if (lane == 63) ws2[w] = s;
            __syncthreads();
            int pre = 0;
            #pragma unroll
            for (int k = 0; k < 16; ++k) pre += (k < w) ? ws2[k] : 0;
            int incl = carry + pre + s;
            int excl = incl - v;
            if (i < NN) {
                offs[i]   = excl;
                cursor[i] = excl;
                float d = (float)(v + 1);
                dis[i]  = rsqrtf(d);
                dinv[i] = (1.0f / d) * FP8_INV_SCALE;
            }
            __syncthreads();
            if (tid == TS - 1) carry = incl;
            __syncthreads();
        }
        if (tid == 0) offs[NN] = carry;
    }
    gbar(sync, 2 * NB_SETUP);

    // phase 3: CSR fill, one edge per thread
    if (gid < EE) {
        int r = erow[gid], c = ecol[gid];
        int p = atomicAdd(&cursor[c], 1);
        cpack[p] = make_int2(r, __float_as_int(dis[r] * dis[c] * FP8_INV_SCALE));
    }
}

// ---------------------------------------------------------------- MFMA GEMM
// BM=64 x BN=256: A read exactly once; B (128KB) L2-resident per XCD.
// C (fp8, x64 via pre-scaled WT): [row][256] sigma-layout, packed dword stores.
#define BK 32
template <int K>
__global__ __launch_bounds__(256)
void k_gemm(const bf16* __restrict__ A, const bf16* __restrict__ BT,
            unsigned char* __restrict__ C) {
    __shared__ __align__(16) short As[64 * BK];      // 4 KB
    __shared__ __align__(16) short Bs[256 * BK];     // 16 KB
    const int tid  = threadIdx.x;
    const int bm   = blockIdx.x * 64;
    const int lane = tid & 63, wave = tid >> 6;
    const int wn   = wave * 64;
    const int fr   = lane & 15, quad = lane >> 4;
    const int r    = tid >> 2;           // 0..63
    const int c    = (tid & 3) * 8;      // shorts: 0,8,16,24

    const bf16* Ap = A  + (size_t)(bm + r) * K + c;
    const bf16* Bp = BT + (size_t)r * K + c;        // rows 0..63 (quarter 0)
    short* AsT = As + tid * 8;                      // byte offset tid*16
    short* BsT = Bs + tid * 8;

    f32x4 acc[4][4] = {};

    for (int k0 = 0; k0 < K; k0 += BK) {
        GLOAD_LDS16(Ap + k0, AsT);
        #pragma unroll
        for (int q = 0; q < 4; ++q)
            GLOAD_LDS16(Bp + (size_t)(q * 64) * K + k0, BsT + q * 64 * BK);
        __syncthreads();
        s16x8 af[4], bfv[4];
        #pragma unroll
        for (int i = 0; i < 4; ++i)
            af[i] = *(const s16x8*)&As[(i * 16 + fr) * BK + quad * 8];
        #pragma unroll
        for (int j = 0; j < 4; ++j)
            bfv[j] = *(const s16x8*)&Bs[(wn + j * 16 + fr) * BK + quad * 8];
        #pragma unroll
        for (int i = 0; i < 4; ++i)
            #pragma unroll
            for (int j = 0; j < 4; ++j)
                acc[i][j] = __builtin_amdgcn_mfma_f32_16x16x32_bf16(
                    af[i], bfv[j], acc[i][j], 0, 0, 0);
        __syncthreads();
    }

    // epilogue: packed dword store per row (sigma-layout); x64 already in WT
    #pragma unroll
    for (int i = 0; i < 4; ++i) {
        int rbase = bm + i * 16 + quad * 4;
        #pragma unroll
        for (int rr = 0; rr < 4; ++rr) {
            int row = rbase + rr;
            if (row >= MREAL) continue;
            unsigned wpack = (unsigned)__builtin_amdgcn_cvt_pk_fp8_f32(
                acc[i][0][rr], acc[i][1][rr], 0, false);
            wpack = (unsigned)__builtin_amdgcn_cvt_pk_fp8_f32(
                acc[i][2][rr], acc[i][3][rr], (int)wpack, true);
            *(unsigned*)&C[(size_t)row * 256 + wn + fr * 4] = wpack;
        }
    }
}

// ------------------------------------------------------- aggregate + elu + fc
// hw fp8 [b*NN+n][256] (x64, sigma-layout); hout bf16 [b*NN+n][256] (sigma).
// Batch-partitioned for XCD L2 residency (blockIdx%8 -> XCD, plane 3.87MB<4MB).
// One node per wave; per-edge metadata wave-uniform -> scalar pipe.
// 16-deep gather unroll: latency-bound (all pipes <50%), double in-flight loads.
#define AGG_GRP 512                       // node groups per batch
#define AGG_STRIDE (AGG_GRP * 4)          // 2048 waves per batch
__global__ __launch_bounds__(256)
void k_agg(const unsigned char* __restrict__ hw, bf16* __restrict__ hout,
           const int* __restrict__ offs, const int2* __restrict__ cpack,
           const float* __restrict__ dinv,
           const float* __restrict__ bias, const float* __restrict__ fcW,
           float* __restrict__ g, int writeH) {
    const int b    = blockIdx.x & 7;
    const int grp  = blockIdx.x >> 3;          // 0..AGG_GRP-1
    const int wid  = threadIdx.x >> 6;         // 0..3
    const int lane = threadIdx.x & 63;
    const int wv   = grp * 4 + wid;            // 0..AGG_STRIDE-1
    const unsigned c4 = lane * 4;

    const unsigned char* hwb = hw + (size_t)b * NN * 256;

    float bias4[4], fw4[4];
    #pragma unroll
    for (int k = 0; k < 4; ++k) {
        int cl = colmap((int)c4 + k);
        bias4[k] = bias[cl];
        fw4[k]   = fcW[3 * cl];
    }

    for (int v0 = wv; v0 < NN; v0 += AGG_STRIDE) {
        const int v   = __builtin_amdgcn_readfirstlane(v0);
        const int beg = __builtin_amdgcn_readfirstlane(offs[v]);
        const int end = __builtin_amdgcn_readfirstlane(offs[v + 1]);
        const float di = dinv[v];
        f32x2 a01, a23;
        {
            unsigned q = *(const unsigned*)(hwb + (((unsigned)v) << 8) + c4);
            f32x2 t0 = __builtin_amdgcn_cvt_pk_f32_fp8(q, false);
            f32x2 t1 = __builtin_amdgcn_cvt_pk_f32_fp8(q, true);
            f32x2 dd = {di, di};
            a01 = dd * t0;
            a23 = dd * t1;
        }

        #define EDGE1(qv, mv) {                                            \
            f32x2 t0 = __builtin_amdgcn_cvt_pk_f32_fp8((qv), false);       \
            f32x2 t1 = __builtin_amdgcn_cvt_pk_f32_fp8((qv), true);        \
            f32x2 mm = {(mv), (mv)};                                       \
            a01 += mm * t0;                                                \
            a23 += mm * t1; }

        int e = beg;
        while (e + 16 <= end) {
            int2 ep[16];
            #pragma unroll
            for (int u = 0; u < 16; ++u) ep[u] = cpack[e + u];
            unsigned q[16];
            #pragma unroll
            for (int u = 0; u < 16; ++u)
                q[u] = *(const unsigned*)(hwb + (((unsigned)ep[u].x) << 8) + c4);
            #pragma unroll
            for (int u = 0; u < 16; ++u) EDGE1(q[u], __int_as_float(ep[u].y));
            e += 16;
        }
        if (e + 8 <= end) {
            int2 ep[8];
            #pragma unroll
            for (int u = 0; u < 8; ++u) ep[u] = cpack[e + u];
            unsigned q[8];
            #pragma unroll
            for (int u = 0; u < 8; ++u)
                q[u] = *(const unsigned*)(hwb + (((unsigned)ep[u].x) << 8) + c4);
            #pragma unroll
            for (int u = 0; u < 8; ++u) EDGE1(q[u], __int_as_float(ep[u].y));
            e += 8;
        }
        if (e + 4 <= end) {
            int2 ep[4];
            #pragma unroll
            for (int u = 0; u < 4; ++u) ep[u] = cpack[e + u];
            unsigned q[4];
            #pragma unroll
            for (int u = 0; u < 4; ++u)
                q[u] = *(const unsigned*)(hwb + (((unsigned)ep[u].x) << 8) + c4);
            #pragma unroll
            for (int u = 0; u < 4; ++u) EDGE1(q[u], __int_as_float(ep[u].y));
            e += 4;
        }
        if (e + 2 <= end) {
            int2 ep0 = cpack[e], ep1 = cpack[e + 1];
            unsigned q0 = *(const unsigned*)(hwb + (((unsigned)ep0.x) << 8) + c4);
            unsigned q1 = *(const unsigned*)(hwb + (((unsigned)ep1.x) << 8) + c4);
            EDGE1(q0, __int_as_float(ep0.y));
            EDGE1(q1, __int_as_float(ep1.y));
            e += 2;
        }
        if (e < end) {
            int2 ep0 = cpack[e];
            unsigned q0 = *(const unsigned*)(hwb + (((unsigned)ep0.x) << 8) + c4);
            EDGE1(q0, __int_as_float(ep0.y));
        }
        #undef EDGE1

        float acc4[4] = {a01[0], a01[1], a23[0], a23[1]};
        float p = 0.f;
        s16x4 o4;
        #pragma unroll
        for (int k = 0; k < 4; ++k) {
            float hv = acc4[k] + bias4[k];
            hv = hv > 0.f ? hv : (__expf(hv) - 1.0f);
            o4[k] = (short)__bfloat16_as_ushort(__float2bfloat16(hv));
            p += hv * fw4[k];
        }
        if (writeH)
            *(s16x4*)&hout[((size_t)b * NN + v) * 256 + c4] = o4;

        #pragma unroll
        for (int off = 32; off; off >>= 1) p += __shfl_xor(p, off);
        if (lane == 0) g[(size_t)b * NN + v] += p;
    }
}

// ------------------------------------------------------------ lin1 partials
__global__ __launch_bounds__(256)
void k_lin1(const float* __restrict__ g, const float* __restrict__ fcb,
            const float* __restrict__ W, float* __restrict__ zpart) {
    const int ny = blockIdx.x;
    const int n0 = ny * NCHUNK;
    const int cnt = min(NCHUNK, NN - n0);
    const int tid = threadIdx.x;
    __shared__ float sg[8][NCHUNK];
    float fb = fcb[0];
    for (int idx = tid; idx < 8 * NCHUNK; idx += 256) {
        int b = idx / NCHUNK, nn = idx - b * NCHUNK;
        sg[b][nn] = (nn < cnt) ? (g[(size_t)b * NN + n0 + nn] + fb) : 0.f;
    }
    __syncthreads();
    float2 acc[8] = {};
    for (int nn = 0; nn < cnt; ++nn) {
        float2 w = *(const float2*)&W[(size_t)(n0 + nn) * HFC + tid * 2];
        #pragma unroll
        for (int b = 0; b < 8; ++b) {
            float gv = sg[b][nn];
            acc[b].x += gv * w.x;
            acc[b].y += gv * w.y;
        }
    }
    #pragma unroll
    for (int b = 0; b < 8; ++b)
        *(float2*)&zpart[(size_t)ny * 4096 + b * 512 + tid * 2] = acc[b];
}

// ----------------------------- lin1 reduce + lin2 + log_softmax (one launch)
// 8 blocks (one per batch) x 512 threads.
__global__ __launch_bounds__(512)
void k_lin2(const float* __restrict__ zpart, const float* __restrict__ l1b,
            const float* __restrict__ W2, const float* __restrict__ l2b,
            float* __restrict__ out) {
    __shared__ float r0[512], r1[512];
    const int b = blockIdx.x, t = threadIdx.x;
    float s = 0.f;
    for (int c = 0; c < NCHUNKS; ++c) s += zpart[(size_t)c * 4096 + b * 512 + t];
    float zv = s + l1b[t];
    zv = zv > 0.f ? zv : (__expf(zv) - 1.0f);
    r0[t] = zv * W2[t * 2 + 0];
    r1[t] = zv * W2[t * 2 + 1];
    __syncthreads();
    for (int st = 256; st; st >>= 1) {
        if (t < st) { r0[t] += r0[t + st]; r1[t] += r1[t + st]; }
        __syncthreads();
    }
    if (t == 0) {
        float o0 = r0[0] + l2b[0], o1 = r1[0] + l2b[1];
        float m = fmaxf(o0, o1);
        float lse = m + logf(expf(o0 - m) + expf(o1 - m));
        out[b * 2 + 0] = o0 - lse;
        out[b * 2 + 1] = o1 - lse;
    }
}

// ---------------------------------------------------------------- launcher
extern "C" void kernel_launch(void* const* d_in, const int* in_sizes, int n_in,
                              void* d_out, int out_size, void* d_ws, size_t ws_size,
                              hipStream_t stream) {
    const float* x    = (const float*)d_in[0];
    const int*   eidx = (const int*)d_in[2];      // [0..E) = row, [E..2E) = col
    const float* gl   = (const float*)d_in[3];
    const float* W1   = (const float*)d_in[4];
    const float* b1   = (const float*)d_in[5];
    const float* W2   = (const float*)d_in[6];
    const float* b2   = (const float*)d_in[7];
    const float* W3   = (const float*)d_in[8];
    const float* b3   = (const float*)d_in[9];
    const float* fcW  = (const float*)d_in[10];
    const float* fcb  = (const float*)d_in[11];
    const float* l1W  = (const float*)d_in[12];
    const float* l1b  = (const float*)d_in[13];
    const float* l2W  = (const float*)d_in[14];
    const float* l2b  = (const float*)d_in[15];
    float* out = (float*)d_out;

    size_t off = 0;
    auto alloc = [&](size_t bytes) {
        void* p = (char*)d_ws + off;
        off += (bytes + 255) & ~(size_t)255;
        return p;
    };
    bf16* bufA          = (bf16*)alloc((size_t)MPAD * 256 * 2);          // 62 MB
    unsigned char* bufC = (unsigned char*)alloc((size_t)MPAD * 256);     // 31 MB
    bf16* W1T      = (bf16*)alloc(256 * K1P * 2);
    bf16* W2T      = (bf16*)alloc(256 * 256 * 2);
    bf16* W3T      = (bf16*)alloc(256 * 256 * 2);
    int*  deg_cnt  = (int*)alloc(NN * 4);
    int*  offs     = (int*)alloc((NN + 1) * 4);
    int*  cursor   = (int*)alloc(NN * 4);
    int*  bsum     = (int*)alloc(SCANB * 4);
    float* dis     = (float*)alloc(NN * 4);
    float* dinv    = (float*)alloc(NN * 4);
    int2* cpack    = (int2*)alloc((size_t)EE * 8);
    float* g       = (float*)alloc((size_t)BSZ * NN * 4);
    int*  sync     = (int*)alloc(64 * 4);

    // zpart aliases bufC: dead after the last k_agg
    float* zpart = (float*)bufC;                              // 3.9 MB

    const int* erow = eidx;
    const int* ecol = eidx + EE;

    // 1. fused prep (h0, WT x3, zero cnt/g/sync)
    k_prep<<<(PREP_TOT + 255) / 256, 256, 0, stream>>>(
        x, gl, bufA, W1, W2, W3, W1T, W2T, W3T, deg_cnt, g, sync);

    // 2. fused setup (deg + scan + dis/dinv + csr), 2 grid barriers
    k_setup<<<NB_SETUP, TS, 0, stream>>>(erow, ecol, deg_cnt, offs, cursor,
                                         bsum, dis, dinv, cpack, sync);

    dim3 ggrid(MPAD / 64);
    dim3 agrid(8 * AGG_GRP);

    // layer 1
    k_gemm<K1P><<<ggrid, 256, 0, stream>>>(bufA, W1T, bufC);
    k_agg<<<agrid, 256, 0, stream>>>(bufC, bufA, offs, cpack, dinv,
                                     b1, fcW + 0, g, 1);
    // layer 2
    k_gemm<256><<<ggrid, 256, 0, stream>>>(bufA, W2T, bufC);
    k_agg<<<agrid, 256, 0, stream>>>(bufC, bufA, offs, cpack, dinv,
                                     b2, fcW + 1, g, 1);
    // layer 3 (h3 not materialized; only fc contribution)
    k_gemm<256><<<ggrid, 256, 0, stream>>>(bufA, W3T, bufC);
    k_agg<<<agrid, 256, 0, stream>>>(bufC, bufA, offs, cpack, dinv,
                                     b3, fcW + 2, g, 0);

    k_lin1<<<NCHUNKS, 256, 0, stream>>>(g, fcb, l1W, zpart);
    k_lin2<<<8, 512, 0, stream>>>(zpart, l1b, l2W, l2b, out);
}

// Round 10
// 439.063 us; speedup vs baseline: 1.1101x; 1.0424x over previous
//
#include <hip/hip_runtime.h>
#include <hip/hip_bf16.h>

using bf16 = __hip_bfloat16;
typedef short s16x8 __attribute__((ext_vector_type(8)));
typedef short s16x4 __attribute__((ext_vector_type(4)));
typedef float f32x4 __attribute__((ext_vector_type(4)));
typedef float f32x2 __attribute__((ext_vector_type(2)));

#define BSZ   8
#define NN    15135
#define FF    64
#define GG    73
#define HH    256
#define EE    242160
#define K1P   160                 // 137 padded to mult of 32
#define MREAL (BSZ * NN)          // 121080
#define MPAD  (946 * 128)         // 121088
#define HFC   512
#define NCHUNK 64
#define NCHUNKS ((NN + NCHUNK - 1) / NCHUNK)   // 237
// fp8 pre-scale: hw stored as e4m3(64*v); x64 folded into WT, 1/64 into csr_norm & dinv
#define FP8_INV_SCALE 0.015625f

#define GLOAD_LDS16(gp, lp)                                                     \
    __builtin_amdgcn_global_load_lds(                                           \
        (const __attribute__((address_space(1))) void*)(gp),                    \
        (__attribute__((address_space(3))) void*)(lp), 16, 0, 0)

// Column permutation applied to the 256-wide GEMM output space.
// Epilogue stores col c at byte position sigma(c) = (c&192) + 4*(c&15) + ((c>>4)&3);
// colmap(p) = sigma^-1(p). Aggregation is element-wise over rows, so a uniform
// column permutation commutes with it; consumers compensate via colmap.
__device__ __forceinline__ int colmap(int p) {
    return (p & 192) | ((p & 3) << 4) | ((p >> 2) & 15);
}

// ------------------------------------------------- fused prep: h0 | WT | zeros
// Zeroes deg counters, csr local counters, g accumulator, sync area.
#define PREP_H0_CNT (MREAL * (K1P / 8))
#define PREP_W1_CNT (256 * K1P)
#define PREP_W23_CNT 65536
#define PREP_TOT (PREP_H0_CNT + PREP_W1_CNT + 2 * PREP_W23_CNT + 2 * NN + MREAL + 1024)
__global__ void k_prep(const float* __restrict__ x, const float* __restrict__ gl,
                       bf16* __restrict__ h0,
                       const float* __restrict__ W1, const float* __restrict__ W2,
                       const float* __restrict__ W3, bf16* __restrict__ W1T,
                       bf16* __restrict__ W2T, bf16* __restrict__ W3T,
                       int* __restrict__ cnt, int* __restrict__ cnt2,
                       float* __restrict__ g, int* __restrict__ sync) {
    int idx = blockIdx.x * blockDim.x + threadIdx.x;
    if (idx < PREP_H0_CNT) {
        int m = idx / (K1P / 8);
        int q = idx - m * (K1P / 8);
        int j0 = q * 8;
        int n = m % NN;
        s16x8 o;
        #pragma unroll
        for (int k = 0; k < 8; ++k) {
            int j = j0 + k;
            float val;
            if (j < FF) val = x[(size_t)m * FF + j];
            else if (j < FF + GG) val = gl[(size_t)n * GG + (j - FF)];
            else val = 0.f;
            o[k] = (short)__bfloat16_as_ushort(__float2bfloat16(val));
        }
        *(s16x8*)&h0[(size_t)m * K1P + j0] = o;
        return;
    }
    idx -= PREP_H0_CNT;
    if (idx < PREP_W1_CNT) {
        int nn = idx / K1P, kk = idx - nn * K1P;
        W1T[idx] = __float2bfloat16(
            kk < FF + GG ? 64.f * W1[(size_t)kk * 256 + nn] : 0.f);
        return;
    }
    idx -= PREP_W1_CNT;
    if (idx < PREP_W23_CNT) {
        int nn = idx >> 8, kk = idx & 255;
        W2T[idx] = __float2bfloat16(64.f * W2[(size_t)colmap(kk) * 256 + nn]);
        return;
    }
    idx -= PREP_W23_CNT;
    if (idx < PREP_W23_CNT) {
        int nn = idx >> 8, kk = idx & 255;
        W3T[idx] = __float2bfloat16(64.f * W3[(size_t)colmap(kk) * 256 + nn]);
        return;
    }
    idx -= PREP_W23_CNT;
    if (idx < NN) { cnt[idx] = 0; return; }
    idx -= NN;
    if (idx < NN) { cnt2[idx] = 0; return; }
    idx -= NN;
    if (idx < MREAL) { g[idx] = 0.f; return; }
    idx -= MREAL;
    if (idx < 1024) sync[idx] = 0;
}

// ------------------------------------------- fused setup: deg+scan+csr
// 240 blocks x 1024 threads; ONE grid barrier (hierarchical: 8 group counters
// on separate cachelines, 30 arrivals each in parallel, then 8 root RMWs --
// the flat 240-RMW-one-line arrive measured ~15us/barrier in R8/R9).
//   phase 1 (all): degree histogram, one atomic/thread   -> gbar
//   phase 2 (all): REDUNDANT full prefix scan into block-local LDS
//                  (NN+1 = 16*946: wave w scans slice w with register carry,
//                   then 16-total fixup; no serial cross-chunk chain).
//                  block 0 additionally writes offs[] to global for k_agg.
//   phase 3 (all): CSR fill; norm from LDS degree diffs (dis/dinv arrays gone)
#define NB_SETUP 240
#define TS 1024
__device__ __forceinline__ void gbar_once(int* sync) {
    __syncthreads();
    if (threadIdx.x == 0) {
        __threadfence();
        int grp = blockIdx.x & 7;                     // 30 blocks per group
        int old = atomicAdd(&sync[16 * (grp + 1)], 1);
        if (old == 29) atomicAdd(&sync[0], 1);
        while (__hip_atomic_load(&sync[0], __ATOMIC_RELAXED,
                                 __HIP_MEMORY_SCOPE_AGENT) < 8)
            __builtin_amdgcn_s_sleep(2);
        __threadfence();
    }
    __syncthreads();
}

__global__ __launch_bounds__(1024)
void k_setup(const int* __restrict__ erow, const int* __restrict__ ecol,
             int* __restrict__ cnt, int* __restrict__ offs,
             int* __restrict__ cnt2, int2* __restrict__ cpack,
             int* __restrict__ sync) {
    __shared__ int soffs[NN + 1];                     // 60.5 KB
    __shared__ int wtot[16], wpre[16];
    const int tid = threadIdx.x, bid = blockIdx.x;
    const int gid = bid * TS + tid;
    const int lane = tid & 63, w = tid >> 6;

    // phase 1: histogram; cache edge endpoints for phase 3
    int myc = 0, myr = 0;
    if (gid < EE) {
        myc = ecol[gid];
        myr = erow[gid];
        atomicAdd(&cnt[myc], 1);
    }
    gbar_once(sync);

    // phase 2: block-local exclusive scan of cnt[0..NN] into soffs
    {
        const int base = w * 946;                     // 16*946 = 15136 = NN+1
        int carry = 0;
        #pragma unroll
        for (int j = 0; j < 15; ++j) {                // 15*64=960 >= 946
            int o = j * 64 + lane;
            int i = base + o;
            bool in = o < 946;
            int v = (in && i < NN) ? cnt[i] : 0;
            int s = v;
            #pragma unroll
            for (int off = 1; off < 64; off <<= 1) {
                int t = __shfl_up(s, off);
                if (lane >= off) s += t;
            }
            if (in) soffs[i] = carry + s - v;         // exclusive
            carry += __shfl(s, 63);
        }
        if (lane == 0) wtot[w] = carry;
    }
    __syncthreads();
    if (w == 0 && lane < 16) {
        int t = wtot[lane];
        int s = t;
        #pragma unroll
        for (int off = 1; off < 16; off <<= 1) {
            int u = __shfl_up(s, off);
            if (lane >= off) s += u;
        }
        wpre[lane] = s - t;                           // exclusive over waves
    }
    __syncthreads();
    {
        const int base = w * 946;
        int add = wpre[w];
        if (add) {
            #pragma unroll
            for (int j = 0; j < 15; ++j) {
                int o = j * 64 + lane;
                if (o < 946) soffs[base + o] += add;
            }
        }
    }
    __syncthreads();

    // block 0 publishes offs for k_agg (kernel boundary handles coherence)
    if (bid == 0)
        for (int i = tid; i <= NN; i += TS) offs[i] = soffs[i];

    // phase 3: CSR fill from LDS offsets; norm from degree diffs
    if (gid < EE) {
        int bc = soffs[myc], dc = soffs[myc + 1] - bc;
        int br = soffs[myr], dr = soffs[myr + 1] - br;
        (void)br;
        int p = atomicAdd(&cnt2[myc], 1);
        float norm = rsqrtf((float)(dr + 1)) * rsqrtf((float)(dc + 1))
                     * FP8_INV_SCALE;
        cpack[bc + p] = make_int2(myr, __float_as_int(norm));
    }
}

// ---------------------------------------------------------------- MFMA GEMM
// BM=64 x BN=256: A read exactly once; B (128KB) L2-resident per XCD.
// C (fp8, x64 via pre-scaled WT): [row][256] sigma-layout, packed dword stores.
#define BK 32
template <int K>
__global__ __launch_bounds__(256)
void k_gemm(const bf16* __restrict__ A, const bf16* __restrict__ BT,
            unsigned char* __restrict__ C) {
    __shared__ __align__(16) short As[64 * BK];      // 4 KB
    __shared__ __align__(16) short Bs[256 * BK];     // 16 KB
    const int tid  = threadIdx.x;
    const int bm   = blockIdx.x * 64;
    const int lane = tid & 63, wave = tid >> 6;
    const int wn   = wave * 64;
    const int fr   = lane & 15, quad = lane >> 4;
    const int r    = tid >> 2;           // 0..63
    const int c    = (tid & 3) * 8;      // shorts: 0,8,16,24

    const bf16* Ap = A  + (size_t)(bm + r) * K + c;
    const bf16* Bp = BT + (size_t)r * K + c;        // rows 0..63 (quarter 0)
    short* AsT = As + tid * 8;                      // byte offset tid*16
    short* BsT = Bs + tid * 8;

    f32x4 acc[4][4] = {};

    for (int k0 = 0; k0 < K; k0 += BK) {
        GLOAD_LDS16(Ap + k0, AsT);
        #pragma unroll
        for (int q = 0; q < 4; ++q)
            GLOAD_LDS16(Bp + (size_t)(q * 64) * K + k0, BsT + q * 64 * BK);
        __syncthreads();
        s16x8 af[4], bfv[4];
        #pragma unroll
        for (int i = 0; i < 4; ++i)
            af[i] = *(const s16x8*)&As[(i * 16 + fr) * BK + quad * 8];
        #pragma unroll
        for (int j = 0; j < 4; ++j)
            bfv[j] = *(const s16x8*)&Bs[(wn + j * 16 + fr) * BK + quad * 8];
        #pragma unroll
        for (int i = 0; i < 4; ++i)
            #pragma unroll
            for (int j = 0; j < 4; ++j)
                acc[i][j] = __builtin_amdgcn_mfma_f32_16x16x32_bf16(
                    af[i], bfv[j], acc[i][j], 0, 0, 0);
        __syncthreads();
    }

    // epilogue: packed dword store per row (sigma-layout); x64 already in WT
    #pragma unroll
    for (int i = 0; i < 4; ++i) {
        int rbase = bm + i * 16 + quad * 4;
        #pragma unroll
        for (int rr = 0; rr < 4; ++rr) {
            int row = rbase + rr;
            if (row >= MREAL) continue;
            unsigned wpack = (unsigned)__builtin_amdgcn_cvt_pk_fp8_f32(
                acc[i][0][rr], acc[i][1][rr], 0, false);
            wpack = (unsigned)__builtin_amdgcn_cvt_pk_fp8_f32(
                acc[i][2][rr], acc[i][3][rr], (int)wpack, true);
            *(unsigned*)&C[(size_t)row * 256 + wn + fr * 4] = wpack;
        }
    }
}

// ------------------------------------------------------- aggregate + elu + fc
// hw fp8 [b*NN+n][256] (x64, sigma-layout); hout bf16 [b*NN+n][256] (sigma).
// Batch-partitioned for XCD L2 residency (blockIdx%8 -> XCD, plane 3.87MB<4MB).
// One node per wave; per-edge metadata wave-uniform -> scalar pipe.
// di derived from offs (deg = end-beg), dinv array eliminated.
#define AGG_GRP 512                       // node groups per batch
#define AGG_STRIDE (AGG_GRP * 4)          // 2048 waves per batch
__global__ __launch_bounds__(256)
void k_agg(const unsigned char* __restrict__ hw, bf16* __restrict__ hout,
           const int* __restrict__ offs, const int2* __restrict__ cpack,
           const float* __restrict__ bias, const float* __restrict__ fcW,
           float* __restrict__ g, int writeH) {
    const int b    = blockIdx.x & 7;
    const int grp  = blockIdx.x >> 3;          // 0..AGG_GRP-1
    const int wid  = threadIdx.x >> 6;         // 0..3
    const int lane = threadIdx.x & 63;
    const int wv   = grp * 4 + wid;            // 0..AGG_STRIDE-1
    const unsigned c4 = lane * 4;

    const unsigned char* hwb = hw + (size_t)b * NN * 256;

    float bias4[4], fw4[4];
    #pragma unroll
    for (int k = 0; k < 4; ++k) {
        int cl = colmap((int)c4 + k);
        bias4[k] = bias[cl];
        fw4[k]   = fcW[3 * cl];
    }

    for (int v0 = wv; v0 < NN; v0 += AGG_STRIDE) {
        const int v   = __builtin_amdgcn_readfirstlane(v0);
        const int beg = __builtin_amdgcn_readfirstlane(offs[v]);
        const int end = __builtin_amdgcn_readfirstlane(offs[v + 1]);
        const float di = FP8_INV_SCALE / (float)(end - beg + 1);
        f32x2 a01, a23;
        {
            unsigned q = *(const unsigned*)(hwb + (((unsigned)v) << 8) + c4);
            f32x2 t0 = __builtin_amdgcn_cvt_pk_f32_fp8(q, false);
            f32x2 t1 = __builtin_amdgcn_cvt_pk_f32_fp8(q, true);
            f32x2 dd = {di, di};
            a01 = dd * t0;
            a23 = dd * t1;
        }

        #define EDGE1(qv, mv) {                                            \
            f32x2 t0 = __builtin_amdgcn_cvt_pk_f32_fp8((qv), false);       \
            f32x2 t1 = __builtin_amdgcn_cvt_pk_f32_fp8((qv), true);        \
            f32x2 mm = {(mv), (mv)};                                       \
            a01 += mm * t0;                                                \
            a23 += mm * t1; }

        int e = beg;
        while (e + 16 <= end) {
            int2 ep[16];
            #pragma unroll
            for (int u = 0; u < 16; ++u) ep[u] = cpack[e + u];
            unsigned q[16];
            #pragma unroll
            for (int u = 0; u < 16; ++u)
                q[u] = *(const unsigned*)(hwb + (((unsigned)ep[u].x) << 8) + c4);
            #pragma unroll
            for (int u = 0; u < 16; ++u) EDGE1(q[u], __int_as_float(ep[u].y));
            e += 16;
        }
        if (e + 8 <= end) {
            int2 ep[8];
            #pragma unroll
            for (int u = 0; u < 8; ++u) ep[u] = cpack[e + u];
            unsigned q[8];
            #pragma unroll
            for (int u = 0; u < 8; ++u)
                q[u] = *(const unsigned*)(hwb + (((unsigned)ep[u].x) << 8) + c4);
            #pragma unroll
            for (int u = 0; u < 8; ++u) EDGE1(q[u], __int_as_float(ep[u].y));
            e += 8;
        }
        if (e + 4 <= end) {
            int2 ep[4];
            #pragma unroll
            for (int u = 0; u < 4; ++u) ep[u] = cpack[e + u];
            unsigned q[4];
            #pragma unroll
            for (int u = 0; u < 4; ++u)
                q[u] = *(const unsigned*)(hwb + (((unsigned)ep[u].x) << 8) + c4);
            #pragma unroll
            for (int u = 0; u < 4; ++u) EDGE1(q[u], __int_as_float(ep[u].y));
            e += 4;
        }
        if (e + 2 <= end) {
            int2 ep0 = cpack[e], ep1 = cpack[e + 1];
            unsigned q0 = *(const unsigned*)(hwb + (((unsigned)ep0.x) << 8) + c4);
            unsigned q1 = *(const unsigned*)(hwb + (((unsigned)ep1.x) << 8) + c4);
            EDGE1(q0, __int_as_float(ep0.y));
            EDGE1(q1, __int_as_float(ep1.y));
            e += 2;
        }
        if (e < end) {
            int2 ep0 = cpack[e];
            unsigned q0 = *(const unsigned*)(hwb + (((unsigned)ep0.x) << 8) + c4);
            EDGE1(q0, __int_as_float(ep0.y));
        }
        #undef EDGE1

        float acc4[4] = {a01[0], a01[1], a23[0], a23[1]};
        float p = 0.f;
        s16x4 o4;
        #pragma unroll
        for (int k = 0; k < 4; ++k) {
            float hv = acc4[k] + bias4[k];
            hv = hv > 0.f ? hv : (__expf(hv) - 1.0f);
            o4[k] = (short)__bfloat16_as_ushort(__float2bfloat16(hv));
            p += hv * fw4[k];
        }
        if (writeH)
            *(s16x4*)&hout[((size_t)b * NN + v) * 256 + c4] = o4;

        #pragma unroll
        for (int off = 32; off; off >>= 1) p += __shfl_xor(p, off);
        if (lane == 0) g[(size_t)b * NN + v] += p;
    }
}

// ------------------------------------------------------------ lin1 partials
__global__ __launch_bounds__(256)
void k_lin1(const float* __restrict__ g, const float* __restrict__ fcb,
            const float* __restrict__ W, float* __restrict__ zpart) {
    const int ny = blockIdx.x;
    const int n0 = ny * NCHUNK;
    const int cnt = min(NCHUNK, NN - n0);
    const int tid = threadIdx.x;
    __shared__ float sg[8][NCHUNK];
    float fb = fcb[0];
    for (int idx = tid; idx < 8 * NCHUNK; idx += 256) {
        int b = idx / NCHUNK, nn = idx - b * NCHUNK;
        sg[b][nn] = (nn < cnt) ? (g[(size_t)b * NN + n0 + nn] + fb) : 0.f;
    }
    __syncthreads();
    float2 acc[8] = {};
    for (int nn = 0; nn < cnt; ++nn) {
        float2 w = *(const float2*)&W[(size_t)(n0 + nn) * HFC + tid * 2];
        #pragma unroll
        for (int b = 0; b < 8; ++b) {
            float gv = sg[b][nn];
            acc[b].x += gv * w.x;
            acc[b].y += gv * w.y;
        }
    }
    #pragma unroll
    for (int b = 0; b < 8; ++b)
        *(float2*)&zpart[(size_t)ny * 4096 + b * 512 + tid * 2] = acc[b];
}

// ----------------------------- lin1 reduce + lin2 + log_softmax (one launch)
// 8 blocks (one per batch) x 512 threads.
__global__ __launch_bounds__(512)
void k_lin2(const float* __restrict__ zpart, const float* __restrict__ l1b,
            const float* __restrict__ W2, const float* __restrict__ l2b,
            float* __restrict__ out) {
    __shared__ float r0[512], r1[512];
    const int b = blockIdx.x, t = threadIdx.x;
    float s = 0.f;
    for (int c = 0; c < NCHUNKS; ++c) s += zpart[(size_t)c * 4096 + b * 512 + t];
    float zv = s + l1b[t];
    zv = zv > 0.f ? zv : (__expf(zv) - 1.0f);
    r0[t] = zv * W2[t * 2 + 0];
    r1[t] = zv * W2[t * 2 + 1];
    __syncthreads();
    for (int st = 256; st; st >>= 1) {
        if (t < st) { r0[t] += r0[t + st]; r1[t] += r1[t + st]; }
        __syncthreads();
    }
    if (t == 0) {
        float o0 = r0[0] + l2b[0], o1 = r1[0] + l2b[1];
        float m = fmaxf(o0, o1);
        float lse = m + logf(expf(o0 - m) + expf(o1 - m));
        out[b * 2 + 0] = o0 - lse;
        out[b * 2 + 1] = o1 - lse;
    }
}

// ---------------------------------------------------------------- launcher
extern "C" void kernel_launch(void* const* d_in, const int* in_sizes, int n_in,
                              void* d_out, int out_size, void* d_ws, size_t ws_size,
                              hipStream_t stream) {
    const float* x    = (const float*)d_in[0];
    const int*   eidx = (const int*)d_in[2];      // [0..E) = row, [E..2E) = col
    const float* gl   = (const float*)d_in[3];
    const float* W1   = (const float*)d_in[4];
    const float* b1   = (const float*)d_in[5];
    const float* W2   = (const float*)d_in[6];
    const float* b2   = (const float*)d_in[7];
    const float* W3   = (const float*)d_in[8];
    const float* b3   = (const float*)d_in[9];
    const float* fcW  = (const float*)d_in[10];
    const float* fcb  = (const float*)d_in[11];
    const float* l1W  = (const float*)d_in[12];
    const float* l1b  = (const float*)d_in[13];
    const float* l2W  = (const float*)d_in[14];
    const float* l2b  = (const float*)d_in[15];
    float* out = (float*)d_out;

    size_t off = 0;
    auto alloc = [&](size_t bytes) {
        void* p = (char*)d_ws + off;
        off += (bytes + 255) & ~(size_t)255;
        return p;
    };
    bf16* bufA          = (bf16*)alloc((size_t)MPAD * 256 * 2);          // 62 MB
    unsigned char* bufC = (unsigned char*)alloc((size_t)MPAD * 256);     // 31 MB
    bf16* W1T      = (bf16*)alloc(256 * K1P * 2);
    bf16* W2T      = (bf16*)alloc(256 * 256 * 2);
    bf16* W3T      = (bf16*)alloc(256 * 256 * 2);
    int*  deg_cnt  = (int*)alloc(NN * 4);
    int*  offs     = (int*)alloc((NN + 1) * 4);
    int*  cnt2     = (int*)alloc(NN * 4);
    int2* cpack    = (int2*)alloc((size_t)EE * 8);
    float* g       = (float*)alloc((size_t)BSZ * NN * 4);
    int*  sync     = (int*)alloc(1024 * 4);

    // zpart aliases bufC: dead after the last k_agg
    float* zpart = (float*)bufC;                              // 3.9 MB

    const int* erow = eidx;
    const int* ecol = eidx + EE;

    // 1. fused prep (h0, WT x3, zero cnt/cnt2/g/sync)
    k_prep<<<(PREP_TOT + 255) / 256, 256, 0, stream>>>(
        x, gl, bufA, W1, W2, W3, W1T, W2T, W3T, deg_cnt, cnt2, g, sync);

    // 2. fused setup (deg + redundant LDS scan + csr), 1 hierarchical barrier
    k_setup<<<NB_SETUP, TS, 0, stream>>>(erow, ecol, deg_cnt, offs, cnt2,
                                         cpack, sync);

    dim3 ggrid(MPAD / 64);
    dim3 agrid(8 * AGG_GRP);

    // layer 1
    k_gemm<K1P><<<ggrid, 256, 0, stream>>>(bufA, W1T, bufC);
    k_agg<<<agrid, 256, 0, stream>>>(bufC, bufA, offs, cpack,
                                     b1, fcW + 0, g, 1);
    // layer 2
    k_gemm<256><<<ggrid, 256, 0, stream>>>(bufA, W2T, bufC);
    k_agg<<<agrid, 256, 0, stream>>>(bufC, bufA, offs, cpack,
                                     b2, fcW + 1, g, 1);
    // layer 3 (h3 not materialized; only fc contribution)
    k_gemm<256><<<ggrid, 256, 0, stream>>>(bufA, W3T, bufC);
    k_agg<<<agrid, 256, 0, stream>>>(bufC, bufA, offs, cpack,
                                     b3, fcW + 2, g, 0);

    k_lin1<<<NCHUNKS, 256, 0, stream>>>(g, fcb, l1W, zpart);
    k_lin2<<<8, 512, 0, stream>>>(zpart, l1b, l2W, l2b, out);
}